// Round 5
// baseline (404.049 us; speedup 1.0000x reference)
//
#include <hip/hip_runtime.h>

// B,H,N,D,E = 2,8,512,16,128
constexpr int CB = 2;
constexpr int CH = 8;
constexpr int CN = 512;
constexpr int CD = 16;
constexpr int CE = 128;
constexpr int CHD = CH * CD;   // 128
constexpr int TM = 64;         // m-rows per z tile (doubled: halves barrier/softmax chains)
constexpr int NTILE = CN / TM; // 8
constexpr int NT = 512;        // 8 waves, one head per wave

typedef __attribute__((ext_vector_type(8))) short short8;   // 8 bf16 (MFMA A/B frag)
typedef __attribute__((ext_vector_type(4))) float f32x4;    // MFMA C/D frag

__device__ __forceinline__ unsigned short f2bf_rne(float x) {
  union { float f; unsigned int u; } a; a.f = x;
  unsigned int r = a.u + 0x7fffu + ((a.u >> 16) & 1u);
  return (unsigned short)(r >> 16);
}

// Truncation split: hi = top 16 bits (exact bf16), lo = (x - hi) truncated to bf16.
__device__ __forceinline__ void split_pair(float x0, float x1,
                                           unsigned int& hi, unsigned int& lo) {
  unsigned int u0 = __float_as_uint(x0), u1 = __float_as_uint(x1);
  unsigned int h0 = u0 & 0xffff0000u, h1 = u1 & 0xffff0000u;
  float l0 = x0 - __uint_as_float(h0);
  float l1 = x1 - __uint_as_float(h1);
  hi = h1 | (u0 >> 16);
  lo = (__float_as_uint(l1) & 0xffff0000u) | (__float_as_uint(l0) >> 16);
}

// 8 consecutive floats (a then b) -> 8 bf16 hi + 8 bf16 lo, memory order.
__device__ __forceinline__ void split8(const float4 a, const float4 b,
                                       short8& hi, short8& lo) {
  union { unsigned int u[4]; short8 s; } H, L;
  split_pair(a.x, a.y, H.u[0], L.u[0]);
  split_pair(a.z, a.w, H.u[1], L.u[1]);
  split_pair(b.x, b.y, H.u[2], L.u[2]);
  split_pair(b.z, b.w, H.u[3], L.u[3]);
  hi = H.s; lo = L.s;
}

#define MFMA(A, B, C) __builtin_amdgcn_mfma_f32_16x16x32_bf16((A), (B), (C), 0, 0, 0)

// R4 structure (8 waves / 1 head each, dbuf LDS, ONE barrier per tile) with:
//  - TM=64: 8 tiles instead of 16 -> half the barriers and softmax dep-chains.
//  - k/v float4 loads hoisted to iteration top: their L2/HBM latency hides
//    under split+barrier+MFMA instead of sitting in the score/PV chains.
// Transposed MFMA: MFMA(W_frag, z_frag) = (z@W)^T, C row = d, col = m.
__global__ __launch_bounds__(NT, 4) void fused_mixedscore_attn(
    const float* __restrict__ q, const float* __restrict__ kk,
    const float* __restrict__ v, const float* __restrict__ z,
    const float* __restrict__ W1, const float* __restrict__ W2,
    float* __restrict__ out)
{
  const int n = blockIdx.x;
  const int b = blockIdx.y;
  const int tid = threadIdx.x;
  const int lane = tid & 63;
  const int h = tid >> 6;         // wave = head
  const int col = lane & 15;      // C col = m-offset
  const int quad = lane >> 4;     // C row-group = d-group

  __shared__ unsigned short zh[2][TM * CE];   // hi bf16, dbuf, 32 KB
  __shared__ unsigned short zl[2][TM * CE];   // lo bf16, dbuf, 32 KB

  const float* gz = z + (size_t)(b * CN + n) * CN * CE;

  // staging: thread handles row sr, 16 consecutive floats starting at sc
  const int sr = tid >> 3;          // 0..63
  const int sc = (tid & 7) * 16;    // 0..112
  const int wb0 = sr * 256 + ((sc * 2) ^ ((sr & 7) << 4));
  const int wb1 = sr * 256 + ((sc * 2 + 16) ^ ((sr & 7) << 4));

  // ---- issue tile-0 loads first (latency hides under W/q setup) ----
  float4 zr0, zr1, zr2, zr3;
  {
    const float* g0 = gz + sr * CE + sc;
    zr0 = *(const float4*)(g0);
    zr1 = *(const float4*)(g0 + 4);
    zr2 = *(const float4*)(g0 + 8);
    zr3 = *(const float4*)(g0 + 12);
  }

  // ---- W1,W2 -> bf16 RNE fragments for this wave's head ----
  short8 B1[4], B2[4];   // [ks]
  {
    const int c = h * CD + col;
#pragma unroll
    for (int ks = 0; ks < 4; ++ks) {
      union { unsigned int u[4]; short8 s; } U1, U2;
#pragma unroll
      for (int jp = 0; jp < 4; ++jp) {
        const int e = ks * 32 + quad * 8 + jp * 2;
        const float a0 = W1[(size_t)e * CHD + c];
        const float a1 = W1[(size_t)(e + 1) * CHD + c];
        const float w0 = W2[(size_t)e * CHD + c];
        const float w1 = W2[(size_t)(e + 1) * CHD + c];
        U1.u[jp] = (unsigned int)f2bf_rne(a0) | ((unsigned int)f2bf_rne(a1) << 16);
        U2.u[jp] = (unsigned int)f2bf_rne(w0) | ((unsigned int)f2bf_rne(w1) << 16);
      }
      B1[ks] = U1.s;
      B2[ks] = U2.s;
    }
  }

  // q for this (n, h): lane needs d = quad*4..+3
  const float4 qv =
      *(const float4*)&q[((size_t)(b * CH + h) * CN + n) * CD + quad * 4];

  // online-softmax state (wave-uniform) + per-lane O partials
  f32x4 Oa = f32x4{0.f, 0.f, 0.f, 0.f};
  float mrun = -3.0e38f;
  float srun = 0.f;

  const float* kbase = kk + ((size_t)(b * CH + h) * CN) * CD + quad * 4;
  const float* vbase = v + ((size_t)(b * CH + h) * CN) * CD + quad * 4;

  for (int t = 0; t < NTILE; ++t) {
    const int cb = t & 1;
    const int m0 = t * TM;

    // ---- early-issue this tile's k and v loads (land before score/PV) ----
    float4 k4[4], v4[4];
#pragma unroll
    for (int mt = 0; mt < 4; ++mt) {
      const size_t m = (size_t)(m0 + mt * 16 + col) * CD;
      k4[mt] = *(const float4*)&kbase[m];
      v4[mt] = *(const float4*)&vbase[m];
    }

    // ---- cooperative split: fp32 regs -> bf16 hi/lo LDS (512 threads) ----
    {
      char* zhb = (char*)&zh[cb][0];
      char* zlb = (char*)&zl[cb][0];
      short8 h8, l8;
      split8(zr0, zr1, h8, l8);
      *(short8*)(zhb + wb0) = h8;
      *(short8*)(zlb + wb0) = l8;
      split8(zr2, zr3, h8, l8);
      *(short8*)(zhb + wb1) = h8;
      *(short8*)(zlb + wb1) = l8;
    }
    __syncthreads();   // single barrier per tile: writes(t) before reads(t);
                       // one-tile wave skew is safe with the double buffer

    // ---- issue tile t+1 loads; they fly under the whole compute phase ----
    if (t + 1 < NTILE) {
      const float* g1 = gz + ((size_t)(t + 1) * TM + sr) * CE + sc;
      zr0 = *(const float4*)(g1);
      zr1 = *(const float4*)(g1 + 4);
      zr2 = *(const float4*)(g1 + 8);
      zr3 = *(const float4*)(g1 + 12);
    }

    // ---- transposed split-bf16 MFMA: acc[d][m] = (z@W)^T for head h ----
    f32x4 acc1[4], acc2[4];   // [mt]
#pragma unroll
    for (int mt = 0; mt < 4; ++mt) {
      acc1[mt] = f32x4{0.f, 0.f, 0.f, 0.f};
      acc2[mt] = f32x4{0.f, 0.f, 0.f, 0.f};
    }

    const char* zhb = (const char*)&zh[cb][0];
    const char* zlb = (const char*)&zl[cb][0];
#pragma unroll
    for (int ks = 0; ks < 4; ++ks) {
#pragma unroll
      for (int mt = 0; mt < 4; ++mt) {
        const int row = mt * 16 + col;
        const int off = row * 256 + ((ks * 64 + quad * 16) ^ ((row & 7) << 4));
        const short8 ah = *(const short8*)(zhb + off);
        const short8 al = *(const short8*)(zlb + off);
        acc1[mt] = MFMA(B1[ks], ah, acc1[mt]);
        acc2[mt] = MFMA(B2[ks], ah, acc2[mt]);
        acc1[mt] = MFMA(B1[ks], al, acc1[mt]);
        acc2[mt] = MFMA(B2[ks], al, acc2[mt]);
      }
    }

    // ---- scores: lane holds 4 d-components for m = m0+mt*16+col ----
    float sc2[4];
#pragma unroll
    for (int mt = 0; mt < 4; ++mt) {
      float p = (qv.x + acc1[mt][0]) * (k4[mt].x + acc2[mt][0]);
      p += (qv.y + acc1[mt][1]) * (k4[mt].y + acc2[mt][1]);
      p += (qv.z + acc1[mt][2]) * (k4[mt].z + acc2[mt][2]);
      p += (qv.w + acc1[mt][3]) * (k4[mt].w + acc2[mt][3]);
      p += __shfl_xor(p, 16);
      p += __shfl_xor(p, 32);
      sc2[mt] = p * 0.25f;   // replicated across the quad's 16 lanes
    }

    // ---- online softmax + PV ----
    {
      float tmax = fmaxf(fmaxf(sc2[0], sc2[1]), fmaxf(sc2[2], sc2[3]));
      tmax = fmaxf(tmax, __shfl_xor(tmax, 1));
      tmax = fmaxf(tmax, __shfl_xor(tmax, 2));
      tmax = fmaxf(tmax, __shfl_xor(tmax, 4));
      tmax = fmaxf(tmax, __shfl_xor(tmax, 8));
      const float mnew = fmaxf(mrun, tmax);
      const float alpha = __expf(mrun - mnew);
      mrun = mnew;
      float e[4];
      float ls = 0.f;
#pragma unroll
      for (int mt = 0; mt < 4; ++mt) {
        e[mt] = __expf(sc2[mt] - mnew);
        ls += e[mt];
      }
      ls += __shfl_xor(ls, 1);
      ls += __shfl_xor(ls, 2);
      ls += __shfl_xor(ls, 4);
      ls += __shfl_xor(ls, 8);
      srun = srun * alpha + ls;

      float px = 0.f, py = 0.f, pz = 0.f, pw = 0.f;
#pragma unroll
      for (int mt = 0; mt < 4; ++mt) {
        px += e[mt] * v4[mt].x;
        py += e[mt] * v4[mt].y;
        pz += e[mt] * v4[mt].z;
        pw += e[mt] * v4[mt].w;
      }
      Oa[0] = Oa[0] * alpha + px;
      Oa[1] = Oa[1] * alpha + py;
      Oa[2] = Oa[2] * alpha + pz;
      Oa[3] = Oa[3] * alpha + pw;
    }
  }

  // ---- finalize: reduce O partials across the 16 m-cols, normalize, store ----
#pragma unroll
  for (int rg = 0; rg < 4; ++rg) {
    float o = Oa[rg];
    o += __shfl_xor(o, 1);
    o += __shfl_xor(o, 2);
    o += __shfl_xor(o, 4);
    o += __shfl_xor(o, 8);
    Oa[rg] = o;
  }
  if (col == 0) {
    const float inv = 1.0f / srun;
    float4 o4;
    o4.x = Oa[0] * inv;
    o4.y = Oa[1] * inv;
    o4.z = Oa[2] * inv;
    o4.w = Oa[3] * inv;
    *(float4*)&out[(size_t)(b * CN + n) * CHD + h * CD + quad * 4] = o4;
  }
}

extern "C" void kernel_launch(void* const* d_in, const int* in_sizes, int n_in,
                              void* d_out, int out_size, void* d_ws, size_t ws_size,
                              hipStream_t stream) {
  const float* q  = (const float*)d_in[0];
  const float* kv = (const float*)d_in[1];
  const float* v  = (const float*)d_in[2];
  const float* z  = (const float*)d_in[3];
  const float* W1 = (const float*)d_in[4];
  const float* W2 = (const float*)d_in[5];
  float* out = (float*)d_out;
  (void)in_sizes; (void)n_in; (void)out_size; (void)d_ws; (void)ws_size;

  dim3 grid(CN, CB);
  hipLaunchKernelGGL(fused_mixedscore_attn, grid, dim3(NT), 0, stream,
                     q, kv, v, z, W1, W2, out);
}

// Round 6
// 389.511 us; speedup vs baseline: 1.0373x; 1.0373x over previous
//
#include <hip/hip_runtime.h>

// B,H,N,D,E = 2,8,512,16,128
constexpr int CB = 2;
constexpr int CH = 8;
constexpr int CN = 512;
constexpr int CD = 16;
constexpr int CE = 128;
constexpr int CHD = CH * CD;   // 128
constexpr int TM = 32;         // m-rows per z tile (R4-proven best)
constexpr int NTILE = CN / TM; // 16
constexpr int NT = 512;        // 8 waves, one head per wave

typedef __attribute__((ext_vector_type(8))) short short8;   // 8 bf16 (MFMA A/B frag)
typedef __attribute__((ext_vector_type(4))) float f32x4;    // MFMA C/D frag

__device__ __forceinline__ unsigned short f2bf_rne(float x) {
  union { float f; unsigned int u; } a; a.f = x;
  unsigned int r = a.u + 0x7fffu + ((a.u >> 16) & 1u);
  return (unsigned short)(r >> 16);
}

// Truncation split: hi = top 16 bits (exact bf16), lo = (x - hi) truncated to bf16.
__device__ __forceinline__ void split_pair(float x0, float x1,
                                           unsigned int& hi, unsigned int& lo) {
  unsigned int u0 = __float_as_uint(x0), u1 = __float_as_uint(x1);
  unsigned int h0 = u0 & 0xffff0000u, h1 = u1 & 0xffff0000u;
  float l0 = x0 - __uint_as_float(h0);
  float l1 = x1 - __uint_as_float(h1);
  hi = h1 | (u0 >> 16);
  lo = (__float_as_uint(l1) & 0xffff0000u) | (__float_as_uint(l0) >> 16);
}

// 8 consecutive floats (a then b) -> 8 bf16 hi + 8 bf16 lo, memory order.
__device__ __forceinline__ void split8(const float4 a, const float4 b,
                                       short8& hi, short8& lo) {
  union { unsigned int u[4]; short8 s; } H, L;
  split_pair(a.x, a.y, H.u[0], L.u[0]);
  split_pair(a.z, a.w, H.u[1], L.u[1]);
  split_pair(b.x, b.y, H.u[2], L.u[2]);
  split_pair(b.z, b.w, H.u[3], L.u[3]);
  hi = H.s; lo = L.s;
}

#define MFMA(A, B, C) __builtin_amdgcn_mfma_f32_16x16x32_bf16((A), (B), (C), 0, 0, 0)

// R4 structure (8 waves / 1 head, TM=32, dbuf LDS, one barrier per tile) with the
// T4 fix: raw s_barrier preceded by lgkmcnt(0) ONLY — no vmcnt(0) drain in the
// main loop — plus a 2-deep z prefetch (ping-pong reg sets A/B, loop unrolled
// x2 for static register indexing). Tile t+2's global loads ride through the
// barriers and get ~2 phases to land; in-flight z bytes per CU double.
// Correctness of the lgkmcnt-only barrier: ds_writes need lgkmcnt(0) before
// s_barrier; z/k/v loads are consumed via register deps (compiler inserts
// exact vmcnt waits at first use). Buffer hazard check: readers of buf X for
// tile t sit between barrier(t) and barrier(t+1); the next writer of buf X
// (tile t+2) sits after barrier(t+1). Safe with one barrier per tile.
__global__ __launch_bounds__(NT, 4) void fused_mixedscore_attn(
    const float* __restrict__ q, const float* __restrict__ kk,
    const float* __restrict__ v, const float* __restrict__ z,
    const float* __restrict__ W1, const float* __restrict__ W2,
    float* __restrict__ out)
{
  const int n = blockIdx.x;
  const int b = blockIdx.y;
  const int tid = threadIdx.x;
  const int lane = tid & 63;
  const int h = tid >> 6;         // wave = head
  const int col = lane & 15;      // C col = m-offset
  const int quad = lane >> 4;     // C row-group = d-group

  __shared__ unsigned short zh[2][TM * CE];   // hi bf16, dbuf, 16 KB
  __shared__ unsigned short zl[2][TM * CE];   // lo bf16, dbuf, 16 KB

  const float* gz = z + (size_t)(b * CN + n) * CN * CE;

  // staging: thread handles row sr, 8 consecutive floats starting at sc
  const int sr = tid >> 4;          // 0..31
  const int sc = (tid & 15) * 8;    // 0..120
  const int wb = sr * 256 + ((sc * 2) ^ ((sr & 7) << 4));

  // ---- prologue: issue tiles 0 (set A) and 1 (set B) ----
  float4 zA0, zA1, zB0, zB1;
  {
    const float* gA = gz + sr * CE + sc;
    zA0 = *(const float4*)(gA);
    zA1 = *(const float4*)(gA + 4);
    const float* gB = gz + ((size_t)TM + sr) * CE + sc;
    zB0 = *(const float4*)(gB);
    zB1 = *(const float4*)(gB + 4);
  }

  // ---- W1,W2 -> bf16 RNE fragments for this wave's head ----
  short8 B1[4], B2[4];   // [ks]
  {
    const int c = h * CD + col;
#pragma unroll
    for (int ks = 0; ks < 4; ++ks) {
      union { unsigned int u[4]; short8 s; } U1, U2;
#pragma unroll
      for (int jp = 0; jp < 4; ++jp) {
        const int e = ks * 32 + quad * 8 + jp * 2;
        const float a0 = W1[(size_t)e * CHD + c];
        const float a1 = W1[(size_t)(e + 1) * CHD + c];
        const float w0 = W2[(size_t)e * CHD + c];
        const float w1 = W2[(size_t)(e + 1) * CHD + c];
        U1.u[jp] = (unsigned int)f2bf_rne(a0) | ((unsigned int)f2bf_rne(a1) << 16);
        U2.u[jp] = (unsigned int)f2bf_rne(w0) | ((unsigned int)f2bf_rne(w1) << 16);
      }
      B1[ks] = U1.s;
      B2[ks] = U2.s;
    }
  }

  // q for this (n, h): lane needs d = quad*4..+3
  const float4 qv =
      *(const float4*)&q[((size_t)(b * CH + h) * CN + n) * CD + quad * 4];

  // online-softmax state (wave-uniform) + per-lane O partials
  f32x4 Oa = f32x4{0.f, 0.f, 0.f, 0.f};
  float mrun = -3.0e38f;
  float srun = 0.f;

  const float* kbase = kk + ((size_t)(b * CH + h) * CN) * CD + quad * 4;
  const float* vbase = v + ((size_t)(b * CH + h) * CN) * CD + quad * 4;

  // stage a reg set into LDS buffer cb (vmcnt waits come from reg deps)
  auto stage = [&](int cb, const float4& r0, const float4& r1) {
    short8 h8, l8;
    split8(r0, r1, h8, l8);
    *(short8*)((char*)&zh[cb][0] + wb) = h8;
    *(short8*)((char*)&zl[cb][0] + wb) = l8;
  };

  // full tile compute from LDS buffer cb (R4-identical numerics)
  auto compute = [&](int m0, int cb) {
    // k/v for this tile: coalesced float4, latency hides under the MFMA phase
    float4 k4[2], v4[2];
#pragma unroll
    for (int mt = 0; mt < 2; ++mt) {
      const size_t moff = (size_t)(m0 + mt * 16 + col) * CD;
      k4[mt] = *(const float4*)&kbase[moff];
      v4[mt] = *(const float4*)&vbase[moff];
    }

    f32x4 acc1[2], acc2[2];
#pragma unroll
    for (int mt = 0; mt < 2; ++mt) {
      acc1[mt] = f32x4{0.f, 0.f, 0.f, 0.f};
      acc2[mt] = f32x4{0.f, 0.f, 0.f, 0.f};
    }

    const char* zhb = (const char*)&zh[cb][0];
    const char* zlb = (const char*)&zl[cb][0];
#pragma unroll
    for (int ks = 0; ks < 4; ++ks) {
#pragma unroll
      for (int mt = 0; mt < 2; ++mt) {
        const int row = mt * 16 + col;
        const int off = row * 256 + ((ks * 64 + quad * 16) ^ ((row & 7) << 4));
        const short8 ah = *(const short8*)(zhb + off);
        const short8 al = *(const short8*)(zlb + off);
        acc1[mt] = MFMA(B1[ks], ah, acc1[mt]);
        acc2[mt] = MFMA(B2[ks], ah, acc2[mt]);
        acc1[mt] = MFMA(B1[ks], al, acc1[mt]);
        acc2[mt] = MFMA(B2[ks], al, acc2[mt]);
      }
    }

    // scores: lane holds 4 d-components for m = m0+mt*16+col
    float sc2[2];
#pragma unroll
    for (int mt = 0; mt < 2; ++mt) {
      float p = (qv.x + acc1[mt][0]) * (k4[mt].x + acc2[mt][0]);
      p += (qv.y + acc1[mt][1]) * (k4[mt].y + acc2[mt][1]);
      p += (qv.z + acc1[mt][2]) * (k4[mt].z + acc2[mt][2]);
      p += (qv.w + acc1[mt][3]) * (k4[mt].w + acc2[mt][3]);
      p += __shfl_xor(p, 16);
      p += __shfl_xor(p, 32);
      sc2[mt] = p * 0.25f;   // replicated across the quad's 16 lanes
    }

    // online softmax + PV
    float tmax = fmaxf(sc2[0], sc2[1]);
    tmax = fmaxf(tmax, __shfl_xor(tmax, 1));
    tmax = fmaxf(tmax, __shfl_xor(tmax, 2));
    tmax = fmaxf(tmax, __shfl_xor(tmax, 4));
    tmax = fmaxf(tmax, __shfl_xor(tmax, 8));
    const float mnew = fmaxf(mrun, tmax);
    const float alpha = __expf(mrun - mnew);
    mrun = mnew;
    const float e0 = __expf(sc2[0] - mnew);
    const float e1 = __expf(sc2[1] - mnew);
    float ls = e0 + e1;
    ls += __shfl_xor(ls, 1);
    ls += __shfl_xor(ls, 2);
    ls += __shfl_xor(ls, 4);
    ls += __shfl_xor(ls, 8);
    srun = srun * alpha + ls;

    Oa[0] = Oa[0] * alpha + e0 * v4[0].x + e1 * v4[1].x;
    Oa[1] = Oa[1] * alpha + e0 * v4[0].y + e1 * v4[1].y;
    Oa[2] = Oa[2] * alpha + e0 * v4[0].z + e1 * v4[1].z;
    Oa[3] = Oa[3] * alpha + e0 * v4[0].w + e1 * v4[1].w;
  };

  for (int tt = 0; tt < NTILE; tt += 2) {
    // ---- EVEN phase: tile tt -> buf0 ----
    stage(0, zA0, zA1);
    asm volatile("s_waitcnt lgkmcnt(0)" ::: "memory");
    __builtin_amdgcn_s_barrier();
    if (tt + 2 < NTILE) {   // refill set A with tile tt+2 (2 phases to land)
      const float* g = gz + ((size_t)(tt + 2) * TM + sr) * CE + sc;
      zA0 = *(const float4*)(g);
      zA1 = *(const float4*)(g + 4);
    }
    compute(tt * TM, 0);

    // ---- ODD phase: tile tt+1 -> buf1 ----
    stage(1, zB0, zB1);
    asm volatile("s_waitcnt lgkmcnt(0)" ::: "memory");
    __builtin_amdgcn_s_barrier();
    if (tt + 3 < NTILE) {   // refill set B with tile tt+3
      const float* g = gz + ((size_t)(tt + 3) * TM + sr) * CE + sc;
      zB0 = *(const float4*)(g);
      zB1 = *(const float4*)(g + 4);
    }
    compute((tt + 1) * TM, 1);
  }

  // ---- finalize: reduce O partials across the 16 m-cols, normalize, store ----
#pragma unroll
  for (int rg = 0; rg < 4; ++rg) {
    float o = Oa[rg];
    o += __shfl_xor(o, 1);
    o += __shfl_xor(o, 2);
    o += __shfl_xor(o, 4);
    o += __shfl_xor(o, 8);
    Oa[rg] = o;
  }
  if (col == 0) {
    const float inv = 1.0f / srun;
    float4 o4;
    o4.x = Oa[0] * inv;
    o4.y = Oa[1] * inv;
    o4.z = Oa[2] * inv;
    o4.w = Oa[3] * inv;
    *(float4*)&out[(size_t)(b * CN + n) * CHD + h * CD + quad * 4] = o4;
  }
}

extern "C" void kernel_launch(void* const* d_in, const int* in_sizes, int n_in,
                              void* d_out, int out_size, void* d_ws, size_t ws_size,
                              hipStream_t stream) {
  const float* q  = (const float*)d_in[0];
  const float* kv = (const float*)d_in[1];
  const float* v  = (const float*)d_in[2];
  const float* z  = (const float*)d_in[3];
  const float* W1 = (const float*)d_in[4];
  const float* W2 = (const float*)d_in[5];
  float* out = (float*)d_out;
  (void)in_sizes; (void)n_in; (void)out_size; (void)d_ws; (void)ws_size;

  dim3 grid(CN, CB);
  hipLaunchKernelGGL(fused_mixedscore_attn, grid, dim3(NT), 0, stream,
                     q, kv, v, z, W1, W2, out);
}